// Round 2
// baseline (1323.375 us; speedup 1.0000x reference)
//
#include <hip/hip_runtime.h>

// Problem constants
#define B_   2
#define NQ_  8192
#define NK_  8192
#define DIN_ 256
#define DH_  256
#define M_   (B_ * NQ_)   // 16384 flattened rows

typedef _Float16 f16x8 __attribute__((ext_vector_type(8)));
typedef unsigned short u16x8 __attribute__((ext_vector_type(8)));
typedef unsigned short u16x4 __attribute__((ext_vector_type(4)));
typedef unsigned int  u32x4 __attribute__((ext_vector_type(4)));
typedef float f32x16 __attribute__((ext_vector_type(16)));

// fp32 -> fp16 bits (RTNE via hardware cvt)
__device__ __forceinline__ unsigned short f2h(float f) {
    _Float16 h = (_Float16)f;
    return __builtin_bit_cast(unsigned short, h);
}

// ---------------------------------------------------------------------------
// Kernel 1: weight convert + transpose.  wt[mat][n][k] = fp16(W[mat][k][n])
// grid (256, 3), block 256 (thread = k)
// ---------------------------------------------------------------------------
__global__ void wt_conv(const float* __restrict__ Wq, const float* __restrict__ Wk,
                        const float* __restrict__ Wv, unsigned short* __restrict__ wt) {
    const int mat = blockIdx.y;
    const int n = blockIdx.x;
    const int k = threadIdx.x;
    const float* W = (mat == 0) ? Wq : (mat == 1) ? Wk : Wv;
    wt[mat * 65536 + n * 256 + k] = f2h(W[k * 256 + n]);
}

// ---------------------------------------------------------------------------
// Kernel 2: projections.  X[16384,256] fp32 @ W[256,256] + b -> fp16.
// mat 0 (q), 1 (k): row-major emb[m][n].  mat 2 (v): transposed v_emb_t[b][d][nq].
// grid (256, 3), block 256 = 4 waves; wave = (pair = rows 32*pair, h = col half)
// 32x32x16 f16 MFMA, A-frags converted from global fp32 on the fly,
// B-frags contiguous 16B loads from transposed fp16 weights (L2-hot).
// ---------------------------------------------------------------------------
__global__ __launch_bounds__(256) void proj(
    const float* __restrict__ xq, const float* __restrict__ xk, const float* __restrict__ xv,
    const float* __restrict__ bq, const float* __restrict__ bk, const float* __restrict__ bv,
    const unsigned short* __restrict__ wt,
    unsigned short* __restrict__ q_emb, unsigned short* __restrict__ k_emb,
    unsigned short* __restrict__ v_emb_t) {
    const int mat = blockIdx.y;
    const float* x    = (mat == 0) ? xq : (mat == 1) ? xk : xv;
    const float* bias = (mat == 0) ? bq : (mat == 1) ? bk : bv;
    const unsigned short* w = wt + mat * 65536;

    const int tid = threadIdx.x;
    const int l = tid & 63, wv = tid >> 6;
    const int pair = wv >> 1, h = wv & 1;
    const int lm = l & 31, lh = l >> 5;
    const int row0 = blockIdx.x * 64;
    const int m = row0 + pair * 32 + lm;

    f32x16 acc[4];
#pragma unroll
    for (int i = 0; i < 4; ++i)
#pragma unroll
        for (int j = 0; j < 16; ++j) acc[i][j] = 0.0f;

#pragma unroll
    for (int ks = 0; ks < 16; ++ks) {
        const float4* ap = (const float4*)(x + (size_t)m * 256 + ks * 16 + lh * 8);
        float4 a0 = ap[0], a1 = ap[1];
        u16x8 au;
        au[0] = f2h(a0.x); au[1] = f2h(a0.y); au[2] = f2h(a0.z); au[3] = f2h(a0.w);
        au[4] = f2h(a1.x); au[5] = f2h(a1.y); au[6] = f2h(a1.z); au[7] = f2h(a1.w);
        f16x8 af = __builtin_bit_cast(f16x8, au);
#pragma unroll
        for (int nt = 0; nt < 4; ++nt) {
            f16x8 bfr = *(const f16x8*)(w + (h * 128 + nt * 32 + lm) * 256 + ks * 16 + lh * 8);
            acc[nt] = __builtin_amdgcn_mfma_f32_32x32x16_f16(af, bfr, acc[nt], 0, 0, 0);
        }
    }

    if (mat < 2) {
        unsigned short* emb = (mat == 0) ? q_emb : k_emb;
#pragma unroll
        for (int nt = 0; nt < 4; ++nt) {
            const int n = h * 128 + nt * 32 + lm;
            const float bsv = bias[n];
#pragma unroll
            for (int r = 0; r < 16; ++r) {
                const int rl = (r & 3) + 8 * (r >> 2) + 4 * lh;
                emb[(size_t)(row0 + pair * 32 + rl) * 256 + n] = f2h(acc[nt][r] + bsv);
            }
        }
    } else {
        const int batch = row0 >> 13;
        const int nqb = (row0 & 8191) + pair * 32;
#pragma unroll
        for (int nt = 0; nt < 4; ++nt) {
            const int n = h * 128 + nt * 32 + lm;   // output feature d
            const float bsv = bias[n];
            unsigned short* dst = v_emb_t + (size_t)batch * DH_ * NQ_ + (size_t)n * NQ_ + nqb;
#pragma unroll
            for (int g = 0; g < 4; ++g) {
                u16x4 pk;
#pragma unroll
                for (int j = 0; j < 4; ++j) pk[j] = f2h(acc[nt][4 * g + j] + bsv);
                *(u16x4*)(dst + 8 * g + 4 * lh) = pk;   // rows nqb+8g+4lh .. +3
            }
        }
    }
}

// ---------------------------------------------------------------------------
// Kernel 3: flash attention (online softmax over full NK).
// grid 256 (= B * NQ/64), block 256 = 4 waves.
// wave: pair = wv>>1 -> Q rows [qb+32*pair, +32); h = wv&1 -> output d half.
// Pair duplicates S=Q·K^T for its 32 rows (keeps softmax stats wave-private),
// splits PV across d halves.  O accumulated transposed (D[d][m], alpha is
// per-lane uniform).  K tile + V^T tile staged in LDS w/ +16B row padding.
// ---------------------------------------------------------------------------
#define BN_ 64
#define KSTRIDE 528    // 64 rows x (512 + 16)
#define VSTRIDE 144    // 256 rows x (128 + 16)
#define KBYTES  (64 * KSTRIDE)            // 33792
#define VBYTES  (256 * VSTRIDE)           // 36864
#define PBYTES  (32 * VSTRIDE)            // 4608 per wave
#define LDS_TOTAL (KBYTES + VBYTES + 4 * PBYTES + 4 * 32 * 4)  // 89600

__global__ __launch_bounds__(256, 1) void flash(
    const unsigned short* __restrict__ q_emb, const unsigned short* __restrict__ k_emb,
    const unsigned short* __restrict__ v_emb_t, float* __restrict__ out) {
    __shared__ __align__(16) char lds_raw[LDS_TOTAL];
    char* kbuf = lds_raw;                       // [64][528]
    char* vbuf = lds_raw + KBYTES;              // [256][144]
    char* pbuf = lds_raw + KBYTES + VBYTES;     // 4 x [32][144]
    float* stats = (float*)(lds_raw + KBYTES + VBYTES + 4 * PBYTES);  // 4 x 32 f32

    const int tid = threadIdx.x;
    const int l = tid & 63, wv = tid >> 6;
    const int pair = wv >> 1, h = wv & 1;
    const int lm = l & 31, lh = l >> 5;

    const int bx = blockIdx.x;
    const int batch = bx >> 7;
    const int qb = (bx & 127) * 64;

    const unsigned short* kg = k_emb + (size_t)batch * NQ_ * 256;
    const unsigned short* vg = v_emb_t + (size_t)batch * DH_ * NQ_;

    // Q fragments resident in registers: rows qb + pair*32 + lm, all 256 k.
    const int mrow = batch * NQ_ + qb + pair * 32 + lm;
    f16x8 qf[16];
#pragma unroll
    for (int ks = 0; ks < 16; ++ks)
        qf[ks] = *(const f16x8*)(q_emb + (size_t)mrow * 256 + ks * 16 + lh * 8);

    f32x16 oacc[4];
#pragma unroll
    for (int i = 0; i < 4; ++i)
#pragma unroll
        for (int j = 0; j < 16; ++j) oacc[i][j] = 0.0f;

    float mstat[16], lstat[16];
#pragma unroll
    for (int r = 0; r < 16; ++r) { mstat[r] = -3.0e38f; lstat[r] = 0.0f; }

    char* myp = pbuf + wv * PBYTES;
    float* myst = stats + wv * 32;

    const int sr = tid >> 5, sc = tid & 31;   // K staging: 8 rows/pass
    const int vr = tid >> 3, vc = tid & 7;    // V staging: 32 rows/pass

    for (int kb = 0; kb < NK_; kb += BN_) {
        __syncthreads();   // previous iteration's LDS reads done
        // ---- stage K tile [64][256] and Vt tile [256][64] ----
#pragma unroll
        for (int p = 0; p < 8; ++p) {
            const int row = p * 8 + sr;
            u32x4 val = *(const u32x4*)(kg + (size_t)(kb + row) * 256 + sc * 8);
            *(u32x4*)(kbuf + row * KSTRIDE + sc * 16) = val;
        }
#pragma unroll
        for (int p = 0; p < 8; ++p) {
            const int d = p * 32 + vr;
            u32x4 val = *(const u32x4*)(vg + (size_t)d * NQ_ + kb + vc * 8);
            *(u32x4*)(vbuf + d * VSTRIDE + vc * 16) = val;
        }
        __syncthreads();

        // ---- S = Q K^T for this wave's 32 rows x 64 cols ----
        f32x16 s0, s1;
#pragma unroll
        for (int j = 0; j < 16; ++j) { s0[j] = 0.0f; s1[j] = 0.0f; }
#pragma unroll
        for (int ks = 0; ks < 16; ++ks) {
            f16x8 kf0 = *(const f16x8*)(kbuf + (0 * 32 + lm) * KSTRIDE + ks * 32 + lh * 16);
            f16x8 kf1 = *(const f16x8*)(kbuf + (1 * 32 + lm) * KSTRIDE + ks * 32 + lh * 16);
            s0 = __builtin_amdgcn_mfma_f32_32x32x16_f16(qf[ks], kf0, s0, 0, 0, 0);
            s1 = __builtin_amdgcn_mfma_f32_32x32x16_f16(qf[ks], kf1, s1, 0, 0, 0);
        }

        // ---- online softmax (rows are wave-private) ----
        float rm[16];
#pragma unroll
        for (int r = 0; r < 16; ++r) rm[r] = fmaxf(s0[r], s1[r]);
#pragma unroll
        for (int mask = 1; mask <= 16; mask <<= 1)
#pragma unroll
            for (int r = 0; r < 16; ++r) rm[r] = fmaxf(rm[r], __shfl_xor(rm[r], mask, 64));

        // p values rounded to fp16 BEFORE the l-sum so numerator (fp16 MFMA)
        // and denominator are consistent -> output stays a convex combination.
        float al[16], ps[16];
        unsigned short hp0[16], hp1[16];
#pragma unroll
        for (int r = 0; r < 16; ++r) {
            const float mn = fmaxf(mstat[r], rm[r]);
            al[r] = __expf(mstat[r] - mn);
            mstat[r] = mn;
            const unsigned short h0 = f2h(__expf(s0[r] - mn));
            const unsigned short h1 = f2h(__expf(s1[r] - mn));
            hp0[r] = h0; hp1[r] = h1;
            ps[r] = (float)__builtin_bit_cast(_Float16, h0) +
                    (float)__builtin_bit_cast(_Float16, h1);
        }
#pragma unroll
        for (int mask = 1; mask <= 16; mask <<= 1)
#pragma unroll
            for (int r = 0; r < 16; ++r) ps[r] += __shfl_xor(ps[r], mask, 64);
#pragma unroll
        for (int r = 0; r < 16; ++r) lstat[r] = lstat[r] * al[r] + ps[r];

        // ---- write P (fp16, [32 m][64 n], +16B pad) + alpha redistribution ----
#pragma unroll
        for (int r = 0; r < 16; ++r) {
            const int mloc = (r & 3) + 8 * (r >> 2) + 4 * lh;
            *(unsigned short*)(myp + mloc * VSTRIDE + (0 * 32 + lm) * 2) = hp0[r];
            *(unsigned short*)(myp + mloc * VSTRIDE + (1 * 32 + lm) * 2) = hp1[r];
        }
        if (lm == 0) {
#pragma unroll
            for (int r = 0; r < 16; ++r) myst[(r & 3) + 8 * (r >> 2) + 4 * lh] = al[r];
        }
        __syncthreads();   // P + stats visible (conservative; wave-private data)

        // ---- rescale O by alpha (per-lane: col m = lm) ----
        const float am = myst[lm];
#pragma unroll
        for (int dt = 0; dt < 4; ++dt)
#pragma unroll
            for (int j = 0; j < 16; ++j) oacc[dt][j] *= am;

        // ---- O^T += V^T P^T : D[d][m], A = Vt frags, B = P frags ----
#pragma unroll
        for (int ks2 = 0; ks2 < 4; ++ks2) {
            f16x8 pf = *(const f16x8*)(myp + lm * VSTRIDE + ks2 * 32 + lh * 16);
#pragma unroll
            for (int dt = 0; dt < 4; ++dt) {
                f16x8 vf = *(const f16x8*)(vbuf + (h * 128 + dt * 32 + lm) * VSTRIDE + ks2 * 32 + lh * 16);
                oacc[dt] = __builtin_amdgcn_mfma_f32_32x32x16_f16(vf, pf, oacc[dt], 0, 0, 0);
            }
        }
    }

    // ---- finalize: divide by l, write out[b][q][d] fp32 ----
    if (lm == 0) {
#pragma unroll
        for (int r = 0; r < 16; ++r) myst[(r & 3) + 8 * (r >> 2) + 4 * lh] = lstat[r];
    }
    __syncthreads();
    const float linv = 1.0f / myst[lm];

    float* orow = out + (size_t)(batch * NQ_ + qb + pair * 32 + lm) * 256;
#pragma unroll
    for (int dt = 0; dt < 4; ++dt) {
#pragma unroll
        for (int g = 0; g < 4; ++g) {
            float4 o4;
            o4.x = oacc[dt][4 * g + 0] * linv;
            o4.y = oacc[dt][4 * g + 1] * linv;
            o4.z = oacc[dt][4 * g + 2] * linv;
            o4.w = oacc[dt][4 * g + 3] * linv;
            *(float4*)(orow + h * 128 + dt * 32 + 8 * g + 4 * lh) = o4;
        }
    }
}

// ---------------------------------------------------------------------------
extern "C" void kernel_launch(void* const* d_in, const int* in_sizes, int n_in,
                              void* d_out, int out_size, void* d_ws, size_t ws_size,
                              hipStream_t stream) {
    const float* q  = (const float*)d_in[0];
    const float* k  = (const float*)d_in[1];
    const float* v  = (const float*)d_in[2];
    const float* Wq = (const float*)d_in[3];
    const float* bq = (const float*)d_in[4];
    const float* Wk = (const float*)d_in[5];
    const float* bk = (const float*)d_in[6];
    const float* Wv = (const float*)d_in[7];
    const float* bv = (const float*)d_in[8];
    float* out = (float*)d_out;

    unsigned short* wt      = (unsigned short*)d_ws;          // 3 * 256*256 fp16
    unsigned short* q_emb   = wt + 3 * 65536;                 // [16384][256]
    unsigned short* k_emb   = q_emb + (size_t)M_ * DH_;       // [16384][256]
    unsigned short* v_emb_t = k_emb + (size_t)M_ * DH_;       // [2][256][8192]

    wt_conv<<<dim3(256, 3), 256, 0, stream>>>(Wq, Wk, Wv, wt);
    proj<<<dim3(256, 3), 256, 0, stream>>>(q, k, v, bq, bk, bv, wt, q_emb, k_emb, v_emb_t);
    flash<<<256, 256, 0, stream>>>(q_emb, k_emb, v_emb_t, out);
}

// Round 3
// 541.555 us; speedup vs baseline: 2.4437x; 2.4437x over previous
//
#include <hip/hip_runtime.h>

// Problem constants
#define B_   2
#define NQ_  8192
#define NK_  8192
#define DIN_ 256
#define DH_  256
#define M_   (B_ * NQ_)   // 16384 flattened rows

typedef _Float16 f16x8 __attribute__((ext_vector_type(8)));
typedef unsigned short u16x8 __attribute__((ext_vector_type(8)));
typedef unsigned short u16x4 __attribute__((ext_vector_type(4)));
typedef unsigned int  u32x4 __attribute__((ext_vector_type(4)));
typedef float f32x16 __attribute__((ext_vector_type(16)));

// fp32 -> fp16 bits (RTNE via hardware cvt)
__device__ __forceinline__ unsigned short f2h(float f) {
    _Float16 h = (_Float16)f;
    return __builtin_bit_cast(unsigned short, h);
}
__device__ __forceinline__ float h2f(unsigned short u) {
    return (float)__builtin_bit_cast(_Float16, u);
}

// ---------------------------------------------------------------------------
// Kernel 1: weight convert + transpose.  wt[mat][n][k] = fp16(W[mat][k][n])
// ---------------------------------------------------------------------------
__global__ void wt_conv(const float* __restrict__ Wq, const float* __restrict__ Wk,
                        const float* __restrict__ Wv, unsigned short* __restrict__ wt) {
    const int mat = blockIdx.y;
    const int n = blockIdx.x;
    const int k = threadIdx.x;
    const float* W = (mat == 0) ? Wq : (mat == 1) ? Wk : Wv;
    wt[mat * 65536 + n * 256 + k] = f2h(W[k * 256 + n]);
}

// ---------------------------------------------------------------------------
// Kernel 2: projections.  X[16384,256] fp32 @ W[256,256] + b -> fp16.
// mat 0 (q), 1 (k): row-major emb[m][n].  mat 2 (v): transposed v_emb_t[b][d][nq].
// ---------------------------------------------------------------------------
__global__ __launch_bounds__(256) void proj(
    const float* __restrict__ xq, const float* __restrict__ xk, const float* __restrict__ xv,
    const float* __restrict__ bq, const float* __restrict__ bk, const float* __restrict__ bv,
    const unsigned short* __restrict__ wt,
    unsigned short* __restrict__ q_emb, unsigned short* __restrict__ k_emb,
    unsigned short* __restrict__ v_emb_t) {
    const int mat = blockIdx.y;
    const float* x    = (mat == 0) ? xq : (mat == 1) ? xk : xv;
    const float* bias = (mat == 0) ? bq : (mat == 1) ? bk : bv;
    const unsigned short* w = wt + mat * 65536;

    const int tid = threadIdx.x;
    const int l = tid & 63, wv = tid >> 6;
    const int pair = wv >> 1, h = wv & 1;
    const int lm = l & 31, lh = l >> 5;
    const int row0 = blockIdx.x * 64;
    const int m = row0 + pair * 32 + lm;

    f32x16 acc[4];
#pragma unroll
    for (int i = 0; i < 4; ++i)
#pragma unroll
        for (int j = 0; j < 16; ++j) acc[i][j] = 0.0f;

#pragma unroll
    for (int ks = 0; ks < 16; ++ks) {
        const float4* ap = (const float4*)(x + (size_t)m * 256 + ks * 16 + lh * 8);
        float4 a0 = ap[0], a1 = ap[1];
        u16x8 au;
        au[0] = f2h(a0.x); au[1] = f2h(a0.y); au[2] = f2h(a0.z); au[3] = f2h(a0.w);
        au[4] = f2h(a1.x); au[5] = f2h(a1.y); au[6] = f2h(a1.z); au[7] = f2h(a1.w);
        f16x8 af = __builtin_bit_cast(f16x8, au);
#pragma unroll
        for (int nt = 0; nt < 4; ++nt) {
            f16x8 bfr = *(const f16x8*)(w + (h * 128 + nt * 32 + lm) * 256 + ks * 16 + lh * 8);
            acc[nt] = __builtin_amdgcn_mfma_f32_32x32x16_f16(af, bfr, acc[nt], 0, 0, 0);
        }
    }

    if (mat < 2) {
        unsigned short* emb = (mat == 0) ? q_emb : k_emb;
#pragma unroll
        for (int nt = 0; nt < 4; ++nt) {
            const int n = h * 128 + nt * 32 + lm;
            const float bsv = bias[n];
#pragma unroll
            for (int r = 0; r < 16; ++r) {
                const int rl = (r & 3) + 8 * (r >> 2) + 4 * lh;
                emb[(size_t)(row0 + pair * 32 + rl) * 256 + n] = f2h(acc[nt][r] + bsv);
            }
        }
    } else {
        const int batch = row0 >> 13;
        const int nqb = (row0 & 8191) + pair * 32;
#pragma unroll
        for (int nt = 0; nt < 4; ++nt) {
            const int n = h * 128 + nt * 32 + lm;   // output feature d
            const float bsv = bias[n];
            unsigned short* dst = v_emb_t + (size_t)batch * DH_ * NQ_ + (size_t)n * NQ_ + nqb;
#pragma unroll
            for (int g = 0; g < 4; ++g) {
                u16x4 pk;
#pragma unroll
                for (int j = 0; j < 4; ++j) pk[j] = f2h(acc[nt][4 * g + j] + bsv);
                *(u16x4*)(dst + 8 * g + 4 * lh) = pk;   // rows nqb+8g+4lh .. +3
            }
        }
    }
}

// ---------------------------------------------------------------------------
// Kernel 3: flash attention, S^T formulation.
// grid 256 (= B * NQ/64), block 512 = 8 waves; role (pair = wv>>2, dq = wv&3).
// S^T = K·Q^T (A = K frags from LDS, B = Q frags register-resident).
// C-layout of S^T: lane holds col q=lm, 32 k-values in regs -> softmax is
// in-register + ONE shfl_xor(32); m/l/alpha are per-lane scalars.
// P written vectorized to per-pair LDS buffer [q][k]; PV reads it back as
// B-fragments (same-wave RAW -> __threadfence_block only, no barrier).
// PV: O^T[d][q] per wave over its d-quarter.  2 barriers/iter.
// ---------------------------------------------------------------------------
#define BN_ 64
#define KSTRIDE 528    // 64 rows x (512 + 16)
#define VSTRIDE 144    // 256 rows x (128 + 16)
#define PSTRIDE 144    // 32 rows x (128 + 16)  (16B-aligned rows)
#define KBYTES  (64 * KSTRIDE)            // 33792
#define VBYTES  (256 * VSTRIDE)           // 36864
#define PBYTES  (32 * PSTRIDE)            // 4608 per pair
#define LDS_TOTAL (KBYTES + VBYTES + 2 * PBYTES)  // 79872

__global__ __launch_bounds__(512, 2) void flash(
    const unsigned short* __restrict__ q_emb, const unsigned short* __restrict__ k_emb,
    const unsigned short* __restrict__ v_emb_t, float* __restrict__ out) {
    __shared__ __align__(16) char lds_raw[LDS_TOTAL];
    char* kbuf = lds_raw;                       // [64][528]
    char* vbuf = lds_raw + KBYTES;              // [256][144]
    char* pbuf = lds_raw + KBYTES + VBYTES;     // 2 x [32][144]

    const int tid = threadIdx.x;
    const int l = tid & 63, wv = tid >> 6;      // wv 0..7
    const int pair = wv >> 2, dq = wv & 3;
    const int lm = l & 31, lh = l >> 5;

    const int bx = blockIdx.x;
    const int batch = bx >> 7;
    const int qb = (bx & 127) * 64;

    const unsigned short* kg = k_emb + (size_t)batch * NQ_ * 256;
    const unsigned short* vg = v_emb_t + (size_t)batch * DH_ * NQ_;

    // Q fragments in registers: q row = qb + pair*32 + lm (same for the 4
    // waves of a pair), all 256 embed dims.
    const int mrow = batch * NQ_ + qb + pair * 32 + lm;
    f16x8 qf[16];
#pragma unroll
    for (int ks = 0; ks < 16; ++ks)
        qf[ks] = *(const f16x8*)(q_emb + (size_t)mrow * 256 + ks * 16 + lh * 8);

    // O^T accumulator: 2 d-tiles (this wave's d-quarter), col q = lm.
    f32x16 oacc[2];
#pragma unroll
    for (int i = 0; i < 2; ++i)
#pragma unroll
        for (int j = 0; j < 16; ++j) oacc[i][j] = 0.0f;

    float mstat = -3.0e38f, lstat = 0.0f;

    char* myp = pbuf + pair * PBYTES;

    // staging indices (512 threads, 64 KB/iter)
    const int sr = tid >> 5, sc = tid & 31;   // K: 16 rows/pass, 4 passes
    const int vr = tid >> 3, vc = tid & 7;    // V: 64 rows/pass, 4 passes

    for (int kb = 0; kb < NK_; kb += BN_) {
        __syncthreads();   // prior iteration's kbuf/vbuf/pbuf reads complete
        // ---- stage K tile [64][256] and Vt tile [256][64] ----
#pragma unroll
        for (int p = 0; p < 4; ++p) {
            const int row = p * 16 + sr;
            u32x4 val = *(const u32x4*)(kg + (size_t)(kb + row) * 256 + sc * 8);
            *(u32x4*)(kbuf + row * KSTRIDE + sc * 16) = val;
        }
#pragma unroll
        for (int p = 0; p < 4; ++p) {
            const int d = p * 64 + vr;
            u32x4 val = *(const u32x4*)(vg + (size_t)d * NQ_ + kb + vc * 8);
            *(u32x4*)(vbuf + d * VSTRIDE + vc * 16) = val;
        }
        __syncthreads();

        // ---- S^T = K Q^T : rows k, cols q (lane: q=lm, 32 k vals in regs) ----
        f32x16 s0, s1;
#pragma unroll
        for (int j = 0; j < 16; ++j) { s0[j] = 0.0f; s1[j] = 0.0f; }
#pragma unroll
        for (int ks = 0; ks < 16; ++ks) {
            f16x8 kf0 = *(const f16x8*)(kbuf + (0 * 32 + lm) * KSTRIDE + ks * 32 + lh * 16);
            f16x8 kf1 = *(const f16x8*)(kbuf + (1 * 32 + lm) * KSTRIDE + ks * 32 + lh * 16);
            s0 = __builtin_amdgcn_mfma_f32_32x32x16_f16(kf0, qf[ks], s0, 0, 0, 0);
            s1 = __builtin_amdgcn_mfma_f32_32x32x16_f16(kf1, qf[ks], s1, 0, 0, 0);
        }

        // ---- per-lane online softmax (q = lm; k spread over this lane + lane^32) ----
        float pm = s0[0];
#pragma unroll
        for (int j = 1; j < 16; ++j) pm = fmaxf(pm, s0[j]);
#pragma unroll
        for (int j = 0; j < 16; ++j) pm = fmaxf(pm, s1[j]);
        pm = fmaxf(pm, __shfl_xor(pm, 32, 64));

        const float mn = fmaxf(mstat, pm);
        const float alpha = __expf(mstat - mn);
        mstat = mn;

        // exp, round to fp16 (consistent numerator/denominator), write P,
        // accumulate partial row sum.
        float psum = 0.0f;
#pragma unroll
        for (int t = 0; t < 2; ++t) {
#pragma unroll
            for (int g = 0; g < 4; ++g) {
                u16x4 pk;
#pragma unroll
                for (int j = 0; j < 4; ++j) {
                    const float sv = (t == 0) ? s0[g * 4 + j] : s1[g * 4 + j];
                    const unsigned short hh = f2h(__expf(sv - mn));
                    pk[j] = hh;
                    psum += h2f(hh);
                }
                // k-base for regs (t, g): 32t + 8g + 4lh  (j is +0..3)
                *(u16x4*)(myp + lm * PSTRIDE + (32 * t + 8 * g + 4 * lh) * 2) = pk;
            }
        }
        psum += __shfl_xor(psum, 32, 64);
        lstat = lstat * alpha + psum;

        __threadfence_block();   // order own-wave P writes before pf reads

        // ---- rescale O by alpha (per-lane scalar) ----
#pragma unroll
        for (int dt = 0; dt < 2; ++dt)
#pragma unroll
            for (int j = 0; j < 16; ++j) oacc[dt][j] *= alpha;

        // ---- O^T += V^T P^T : A = Vt frags (d rows), B = P frags ----
#pragma unroll
        for (int ks2 = 0; ks2 < 4; ++ks2) {
            f16x8 pf = *(const f16x8*)(myp + lm * PSTRIDE + ks2 * 32 + lh * 16);
#pragma unroll
            for (int dt = 0; dt < 2; ++dt) {
                f16x8 vf = *(const f16x8*)(vbuf + (dq * 64 + dt * 32 + lm) * VSTRIDE + ks2 * 32 + lh * 16);
                oacc[dt] = __builtin_amdgcn_mfma_f32_32x32x16_f16(vf, pf, oacc[dt], 0, 0, 0);
            }
        }
    }

    // ---- finalize: divide by l (per-lane scalar), write out[b][q][d] fp32 ----
    const float linv = 1.0f / lstat;
    float* orow = out + (size_t)(batch * NQ_ + qb + pair * 32 + lm) * 256;
#pragma unroll
    for (int dt = 0; dt < 2; ++dt) {
#pragma unroll
        for (int g = 0; g < 4; ++g) {
            float4 o4;
            o4.x = oacc[dt][4 * g + 0] * linv;
            o4.y = oacc[dt][4 * g + 1] * linv;
            o4.z = oacc[dt][4 * g + 2] * linv;
            o4.w = oacc[dt][4 * g + 3] * linv;
            *(float4*)(orow + dq * 64 + dt * 32 + 8 * g + 4 * lh) = o4;
        }
    }
}

// ---------------------------------------------------------------------------
extern "C" void kernel_launch(void* const* d_in, const int* in_sizes, int n_in,
                              void* d_out, int out_size, void* d_ws, size_t ws_size,
                              hipStream_t stream) {
    const float* q  = (const float*)d_in[0];
    const float* k  = (const float*)d_in[1];
    const float* v  = (const float*)d_in[2];
    const float* Wq = (const float*)d_in[3];
    const float* bq = (const float*)d_in[4];
    const float* Wk = (const float*)d_in[5];
    const float* bk = (const float*)d_in[6];
    const float* Wv = (const float*)d_in[7];
    const float* bv = (const float*)d_in[8];
    float* out = (float*)d_out;

    unsigned short* wt      = (unsigned short*)d_ws;          // 3 * 256*256 fp16
    unsigned short* q_emb   = wt + 3 * 65536;                 // [16384][256]
    unsigned short* k_emb   = q_emb + (size_t)M_ * DH_;       // [16384][256]
    unsigned short* v_emb_t = k_emb + (size_t)M_ * DH_;       // [2][256][8192]

    wt_conv<<<dim3(256, 3), 256, 0, stream>>>(Wq, Wk, Wv, wt);
    proj<<<dim3(256, 3), 256, 0, stream>>>(q, k, v, bq, bk, bv, wt, q_emb, k_emb, v_emb_t);
    flash<<<256, 512, 0, stream>>>(q_emb, k_emb, v_emb_t, out);
}

// Round 4
// 368.371 us; speedup vs baseline: 3.5925x; 1.4701x over previous
//
#include <hip/hip_runtime.h>

// Problem constants
#define B_   2
#define NQ_  8192
#define NK_  8192
#define DIN_ 256
#define DH_  256
#define M_   (B_ * NQ_)   // 16384 flattened rows

typedef _Float16 f16x8 __attribute__((ext_vector_type(8)));
typedef unsigned short u16x8 __attribute__((ext_vector_type(8)));
typedef unsigned short u16x4 __attribute__((ext_vector_type(4)));
typedef unsigned int  u32x4 __attribute__((ext_vector_type(4)));
typedef float f32x16 __attribute__((ext_vector_type(16)));

// fp32 -> fp16 bits (RTNE via hardware cvt)
__device__ __forceinline__ unsigned short f2h(float f) {
    _Float16 h = (_Float16)f;
    return __builtin_bit_cast(unsigned short, h);
}
__device__ __forceinline__ float h2f(unsigned short u) {
    return (float)__builtin_bit_cast(_Float16, u);
}

// ---------------------------------------------------------------------------
// Kernel 1: weight convert + transpose via LDS tile (both sides coalesced).
// wt[mat][n][k] = fp16(W[mat][k][n]).  grid (4,4,3), block 256.
// ---------------------------------------------------------------------------
__global__ void wt_conv(const float* __restrict__ Wq, const float* __restrict__ Wk,
                        const float* __restrict__ Wv, unsigned short* __restrict__ wt) {
    __shared__ float tile[64][65];
    const int mat = blockIdx.z;
    const int k0 = blockIdx.x * 64, n0 = blockIdx.y * 64;
    const float* W = (mat == 0) ? Wq : (mat == 1) ? Wk : Wv;
#pragma unroll
    for (int p = 0; p < 16; ++p) {
        const int idx = p * 256 + threadIdx.x;
        const int r = idx >> 6, c = idx & 63;
        tile[r][c] = W[(k0 + r) * 256 + n0 + c];
    }
    __syncthreads();
#pragma unroll
    for (int p = 0; p < 16; ++p) {
        const int idx = p * 256 + threadIdx.x;
        const int nr = idx >> 6, kc = idx & 63;
        wt[mat * 65536 + (n0 + nr) * 256 + k0 + kc] = f2h(tile[kc][nr]);
    }
}

// ---------------------------------------------------------------------------
// Kernel 2: projections.  X[16384,256] fp32 @ W[256,256] + b -> fp16.
// mat 0 (q), 1 (k): row-major emb[m][n].  mat 2 (v): transposed v_emb_t[b][d][nq].
// ---------------------------------------------------------------------------
__global__ __launch_bounds__(256) void proj(
    const float* __restrict__ xq, const float* __restrict__ xk, const float* __restrict__ xv,
    const float* __restrict__ bq, const float* __restrict__ bk, const float* __restrict__ bv,
    const unsigned short* __restrict__ wt,
    unsigned short* __restrict__ q_emb, unsigned short* __restrict__ k_emb,
    unsigned short* __restrict__ v_emb_t) {
    const int mat = blockIdx.y;
    const float* x    = (mat == 0) ? xq : (mat == 1) ? xk : xv;
    const float* bias = (mat == 0) ? bq : (mat == 1) ? bk : bv;
    const unsigned short* w = wt + mat * 65536;

    const int tid = threadIdx.x;
    const int l = tid & 63, wv = tid >> 6;
    const int pair = wv >> 1, h = wv & 1;
    const int lm = l & 31, lh = l >> 5;
    const int row0 = blockIdx.x * 64;
    const int m = row0 + pair * 32 + lm;

    f32x16 acc[4];
#pragma unroll
    for (int i = 0; i < 4; ++i)
#pragma unroll
        for (int j = 0; j < 16; ++j) acc[i][j] = 0.0f;

#pragma unroll
    for (int ks = 0; ks < 16; ++ks) {
        const float4* ap = (const float4*)(x + (size_t)m * 256 + ks * 16 + lh * 8);
        float4 a0 = ap[0], a1 = ap[1];
        u16x8 au;
        au[0] = f2h(a0.x); au[1] = f2h(a0.y); au[2] = f2h(a0.z); au[3] = f2h(a0.w);
        au[4] = f2h(a1.x); au[5] = f2h(a1.y); au[6] = f2h(a1.z); au[7] = f2h(a1.w);
        f16x8 af = __builtin_bit_cast(f16x8, au);
#pragma unroll
        for (int nt = 0; nt < 4; ++nt) {
            f16x8 bfr = *(const f16x8*)(w + (h * 128 + nt * 32 + lm) * 256 + ks * 16 + lh * 8);
            acc[nt] = __builtin_amdgcn_mfma_f32_32x32x16_f16(af, bfr, acc[nt], 0, 0, 0);
        }
    }

    if (mat < 2) {
        unsigned short* emb = (mat == 0) ? q_emb : k_emb;
#pragma unroll
        for (int nt = 0; nt < 4; ++nt) {
            const int n = h * 128 + nt * 32 + lm;
            const float bsv = bias[n];
#pragma unroll
            for (int r = 0; r < 16; ++r) {
                const int rl = (r & 3) + 8 * (r >> 2) + 4 * lh;
                emb[(size_t)(row0 + pair * 32 + rl) * 256 + n] = f2h(acc[nt][r] + bsv);
            }
        }
    } else {
        const int batch = row0 >> 13;
        const int nqb = (row0 & 8191) + pair * 32;
#pragma unroll
        for (int nt = 0; nt < 4; ++nt) {
            const int n = h * 128 + nt * 32 + lm;   // output feature d
            const float bsv = bias[n];
            unsigned short* dst = v_emb_t + (size_t)batch * DH_ * NQ_ + (size_t)n * NQ_ + nqb;
#pragma unroll
            for (int g = 0; g < 4; ++g) {
                u16x4 pk;
#pragma unroll
                for (int j = 0; j < 4; ++j) pk[j] = f2h(acc[nt][4 * g + j] + bsv);
                *(u16x4*)(dst + 8 * g + 4 * lh) = pk;   // rows nqb+8g+4lh .. +3
            }
        }
    }
}

// ---------------------------------------------------------------------------
// Kernel 3: flash attention, S^T formulation, BN=128, ZERO S duplication.
// grid 256 (= B * NQ/64), block 512 = 8 waves; role (kq = wv>>1, pair = wv&1).
// Each wave owns one distinct 32k x 32q S^T tile (A = K frags from LDS,
// B = Q frags register-resident).  Cross-wave softmax via tiny LDS stats
// ([pair][q][kq] float4).  PV: wave = d-quarter kq x q-tile pair, zero dup.
// Next K/V tile prefetched into registers right after staging barrier.
// 4 barriers/iter, 64 iters.
// ---------------------------------------------------------------------------
#define BN_ 128
#define KSTRIDE 528    // 128 rows x (512 + 16)   : 33 granules (odd) -> conflict-free b128
#define VSTRIDE 272    // 256 rows x (256 + 16)   : 17 granules
#define PSTRIDE 272    // 64 rows  x (256 + 16)
#define KBYTES  (128 * KSTRIDE)            // 67584
#define VBYTES  (256 * VSTRIDE)            // 69632
#define PBYTES  (64 * PSTRIDE)             // 17408
#define STAT_OFF (KBYTES + VBYTES + PBYTES)        // 154624 (16B aligned)
#define LDS_TOTAL (STAT_OFF + 2048)                // 156672 <= 160 KiB

__global__ __launch_bounds__(512, 2) void flash(
    const unsigned short* __restrict__ q_emb, const unsigned short* __restrict__ k_emb,
    const unsigned short* __restrict__ v_emb_t, float* __restrict__ out) {
    __shared__ __align__(16) char lds_raw[LDS_TOTAL];
    char* kbuf = lds_raw;                       // [128][528]
    char* vbuf = lds_raw + KBYTES;              // [256][272]
    char* pbuf = lds_raw + KBYTES + VBYTES;     // [64][272]
    float* smax = (float*)(lds_raw + STAT_OFF); // [2][32][4]
    float* ssum = smax + 256;                   // [2][32][4]

    const int tid = threadIdx.x;
    const int l = tid & 63, wv = tid >> 6;      // wv 0..7
    const int kq = wv >> 1, pair = wv & 1;      // k-tile / q-tile role
    const int lm = l & 31, lh = l >> 5;

    const int bx = blockIdx.x;
    const int batch = bx >> 7;
    const int qb = (bx & 127) * 64;

    const unsigned short* kg = k_emb + (size_t)batch * NQ_ * 256;
    const unsigned short* vg = v_emb_t + (size_t)batch * DH_ * NQ_;

    // Q fragments register-resident: q row = qb + pair*32 + lm, all 256 dims.
    const int mrow = batch * NQ_ + qb + pair * 32 + lm;
    f16x8 qf[16];
#pragma unroll
    for (int ks = 0; ks < 16; ++ks)
        qf[ks] = *(const f16x8*)(q_emb + (size_t)mrow * 256 + ks * 16 + lh * 8);

    // O^T accumulator: this wave's d-quarter (kq), q cols = pair tile.
    f32x16 oacc[2];
#pragma unroll
    for (int i = 0; i < 2; ++i)
#pragma unroll
        for (int j = 0; j < 16; ++j) oacc[i][j] = 0.0f;

    float mstat = -3.0e38f, lstat = 0.0f;

    // staging indices (512 threads; K 16 rows/pass x8, V 32 rows/pass x8)
    const int sr = tid >> 5, sc = tid & 31;
    const int vr = tid >> 4, vc = tid & 15;

    // prefetch tile 0 into registers
    u32x4 kpre[8], vpre[8];
#pragma unroll
    for (int p = 0; p < 8; ++p)
        kpre[p] = *(const u32x4*)(kg + (size_t)(p * 16 + sr) * 256 + sc * 8);
#pragma unroll
    for (int p = 0; p < 8; ++p)
        vpre[p] = *(const u32x4*)(vg + (size_t)(p * 32 + vr) * NQ_ + vc * 8);

    for (int kb = 0; kb < NK_; kb += BN_) {
        __syncthreads();   // B1: prior kbuf/vbuf/pbuf/stat reads done
        // ---- write prefetched K tile [128][256] and Vt tile [256][128] ----
#pragma unroll
        for (int p = 0; p < 8; ++p)
            *(u32x4*)(kbuf + (p * 16 + sr) * KSTRIDE + sc * 16) = kpre[p];
#pragma unroll
        for (int p = 0; p < 8; ++p)
            *(u32x4*)(vbuf + (p * 32 + vr) * VSTRIDE + vc * 16) = vpre[p];
        __syncthreads();   // B2: tiles visible

        // ---- issue next-tile global prefetch (overlaps S/softmax/PV) ----
        const int nkb = kb + BN_;
        if (nkb < NK_) {
#pragma unroll
            for (int p = 0; p < 8; ++p)
                kpre[p] = *(const u32x4*)(kg + (size_t)(nkb + p * 16 + sr) * 256 + sc * 8);
#pragma unroll
            for (int p = 0; p < 8; ++p)
                vpre[p] = *(const u32x4*)(vg + (size_t)(p * 32 + vr) * NQ_ + nkb + vc * 8);
        }

        // ---- S^T tile (32k x 32q): A = K rows kq*32+lm, B = qf ----
        f32x16 s;
#pragma unroll
        for (int j = 0; j < 16; ++j) s[j] = 0.0f;
#pragma unroll
        for (int ks = 0; ks < 16; ++ks) {
            f16x8 kf = *(const f16x8*)(kbuf + (kq * 32 + lm) * KSTRIDE + ks * 32 + lh * 16);
            s = __builtin_amdgcn_mfma_f32_32x32x16_f16(kf, qf[ks], s, 0, 0, 0);
        }

        // ---- partial max over this wave's 32 k (per lane: q = lm) ----
        float pm = s[0];
#pragma unroll
        for (int j = 1; j < 16; ++j) pm = fmaxf(pm, s[j]);
        pm = fmaxf(pm, __shfl_xor(pm, 32, 64));
        if (lh == 0) smax[(pair * 32 + lm) * 4 + kq] = pm;
        __syncthreads();   // B3: all partial maxes visible

        const float4 m4 = *(const float4*)&smax[(pair * 32 + lm) * 4];
        const float gm = fmaxf(fmaxf(m4.x, m4.y), fmaxf(m4.z, m4.w));
        const float mn = fmaxf(mstat, gm);
        const float alpha = __expf(mstat - mn);
        mstat = mn;

        // ---- exp own tile (fp16-rounded for num/denom consistency),
        //      write P^T tile [q=pair*32+lm][k=kq*32 + ...], partial sum ----
        float psum = 0.0f;
#pragma unroll
        for (int g = 0; g < 4; ++g) {
            u16x4 pk;
#pragma unroll
            for (int j = 0; j < 4; ++j) {
                const unsigned short hh = f2h(__expf(s[g * 4 + j] - mn));
                pk[j] = hh;
                psum += h2f(hh);
            }
            *(u16x4*)(pbuf + (pair * 32 + lm) * PSTRIDE + (kq * 32 + 8 * g + 4 * lh) * 2) = pk;
        }
        psum += __shfl_xor(psum, 32, 64);
        if (lh == 0) ssum[(pair * 32 + lm) * 4 + kq] = psum;
        __syncthreads();   // B4: P tiles + partial sums visible

        const float4 s4 = *(const float4*)&ssum[(pair * 32 + lm) * 4];
        lstat = lstat * alpha + (s4.x + s4.y) + (s4.z + s4.w);

        // ---- rescale O by alpha (per-lane scalar) ----
#pragma unroll
        for (int dt = 0; dt < 2; ++dt)
#pragma unroll
            for (int j = 0; j < 16; ++j) oacc[dt][j] *= alpha;

        // ---- O^T += V^T P^T over 128 k : A = Vt frags (d rows), B = P frags ----
#pragma unroll
        for (int ks2 = 0; ks2 < 8; ++ks2) {
            f16x8 pf = *(const f16x8*)(pbuf + (pair * 32 + lm) * PSTRIDE + ks2 * 32 + lh * 16);
#pragma unroll
            for (int dt = 0; dt < 2; ++dt) {
                f16x8 vf = *(const f16x8*)(vbuf + (kq * 64 + dt * 32 + lm) * VSTRIDE + ks2 * 32 + lh * 16);
                oacc[dt] = __builtin_amdgcn_mfma_f32_32x32x16_f16(vf, pf, oacc[dt], 0, 0, 0);
            }
        }
    }

    // ---- finalize: divide by l (per-lane scalar), write out[b][q][d] fp32 ----
    const float linv = 1.0f / lstat;
    float* orow = out + (size_t)(batch * NQ_ + qb + pair * 32 + lm) * 256;
#pragma unroll
    for (int dt = 0; dt < 2; ++dt) {
#pragma unroll
        for (int g = 0; g < 4; ++g) {
            float4 o4;
            o4.x = oacc[dt][4 * g + 0] * linv;
            o4.y = oacc[dt][4 * g + 1] * linv;
            o4.z = oacc[dt][4 * g + 2] * linv;
            o4.w = oacc[dt][4 * g + 3] * linv;
            *(float4*)(orow + kq * 64 + dt * 32 + 8 * g + 4 * lh) = o4;
        }
    }
}

// ---------------------------------------------------------------------------
extern "C" void kernel_launch(void* const* d_in, const int* in_sizes, int n_in,
                              void* d_out, int out_size, void* d_ws, size_t ws_size,
                              hipStream_t stream) {
    const float* q  = (const float*)d_in[0];
    const float* k  = (const float*)d_in[1];
    const float* v  = (const float*)d_in[2];
    const float* Wq = (const float*)d_in[3];
    const float* bq = (const float*)d_in[4];
    const float* Wk = (const float*)d_in[5];
    const float* bk = (const float*)d_in[6];
    const float* Wv = (const float*)d_in[7];
    const float* bv = (const float*)d_in[8];
    float* out = (float*)d_out;

    unsigned short* wt      = (unsigned short*)d_ws;          // 3 * 256*256 fp16
    unsigned short* q_emb   = wt + 3 * 65536;                 // [16384][256]
    unsigned short* k_emb   = q_emb + (size_t)M_ * DH_;       // [16384][256]
    unsigned short* v_emb_t = k_emb + (size_t)M_ * DH_;       // [2][256][8192]

    wt_conv<<<dim3(4, 4, 3), 256, 0, stream>>>(Wq, Wk, Wv, wt);
    proj<<<dim3(256, 3), 256, 0, stream>>>(q, k, v, bq, bk, bv, wt, q_emb, k_emb, v_emb_t);
    flash<<<256, 512, 0, stream>>>(q_emb, k_emb, v_emb_t, out);
}